// Round 3
// baseline (202.975 us; speedup 1.0000x reference)
//
#include <hip/hip_runtime.h>

#define V 16
#define MAXN 64
#define WAVES_PER_BLOCK 4

__device__ __forceinline__ float safe_(float d) { return (d == 0.0f) ? 1.0f : d; }

// popcount(m & ((1<<lane)-1)) in 2 instructions
__device__ __forceinline__ int lower_popcount(unsigned long long m) {
    return __builtin_amdgcn_mbcnt_hi((unsigned)(m >> 32),
           __builtin_amdgcn_mbcnt_lo((unsigned)m, 0));
}

// One wave (64 lanes) per polygon pair. lane = vertex slot (MAXN==64).
//
// Single-kernel fused version, NO memset node (R1 showed a captured
// hipMemsetAsync coincided with a 128 MiB copyBuffer in the replayed graph,
// +23 us). Counter reset is replaced by the poison-base trick:
//   - harness re-poisons d_ws with a constant-pattern fillBuffer each replay,
//     so the untouched word at byte offset 64 (multiple of any fill-pattern
//     period 1/2/4/8/16B) equals the counter's initial value;
//   - each block reads base=ws32[16], fetch_adds ws32[0]; the unique block
//     with (old-base)==nblocks-1 (unsigned, wrap-safe) is last;
//   - the last block RESTORES ws32[0]=base after finalizing, so the scheme
//     also survives replays without re-poisoning.
// Failure mode is visible (out unwritten), never a hang — no spin loops.
//
// NOTE: no explicit LDS fences in the clip loop — DS ops from a single wave
// are processed in program order by the LDS unit; compiler inserts lgkmcnt.
__global__ __launch_bounds__(256) void poly_iou_fused_kernel(
    const float* __restrict__ output,   // [B, 2V, HW]
    const float* __restrict__ mask,     // [B, K]
    const int*   __restrict__ ind,      // [B, K]
    const float* __restrict__ target,   // [B, K, 2V]
    unsigned int* __restrict__ ws_u32,  // workspace as u32: [0]=counter, [16]=base word
    float* __restrict__ iou_res,        // ws + 256 B: iou * mask per pair [BK]
    float* __restrict__ out,            // scalar loss
    int BK, int K, int HW, int nblocks)
{
    __shared__ float bufx[WAVES_PER_BLOCK][MAXN];
    __shared__ float bufy[WAVES_PER_BLOCK][MAXN];
    __shared__ float red_a[WAVES_PER_BLOCK], red_c[WAVES_PER_BLOCK];
    __shared__ int   last_flag;

    const int lane = threadIdx.x & 63;
    const int wave = threadIdx.x >> 6;
    int pair = blockIdx.x * WAVES_PER_BLOCK + wave;
    const bool live = pair < BK;
    if (!live) pair = 0;                 // keep wave running (uniform control)
    // pair is wave-uniform by construction → pin it to an SGPR so ind/mask
    // loads go down the scalar-memory path, off the vector critical path.
    const int pu = __builtin_amdgcn_readfirstlane(pair);
    const int b  = pu / K;

    const int   idx  = ind[pu];          // scalar load, issued early
    const float mval = mask[pu];         // scalar load, issued early

    // ---- load subject (pred, gathered) and clip (target) polygons ----
    float px = 0.0f, py = 0.0f;          // working poly[lane]
    float sx = 0.0f, sy = 0.0f;          // subject copy (for a_p)
    float cx = 0.0f, cy = 0.0f;          // clip vertex   (for edges + a_g)
    if (lane < V) {
        const float* ob = output + ((size_t)b * (2 * V)) * (size_t)HW;
        sx = ob[(size_t)(2 * lane) * HW + idx];
        sy = ob[(size_t)(2 * lane + 1) * HW + idx];
        const float2 t2 = ((const float2*)(target + (size_t)pu * (2 * V)))[lane];
        cx = t2.x;
        cy = t2.y;
        px = sx; py = sy;
    }
    int n = V;

    // ---- Sutherland–Hodgman clip: 16 edges (c1=clip[t-1], c2=clip[t]) ----
    for (int t = 0; t < V; ++t) {
        if (n == 0) break;               // wave-uniform

        const int t1 = (t + V - 1) & (V - 1);
        const float c1x = __shfl(cx, t1), c1y = __shfl(cy, t1);
        const float c2x = __shfl(cx, t),  c2y = __shfl(cy, t);

        // prev index: (lane-1) mod n; only lanes < n matter
        const int pidx = (lane == 0) ? (n - 1) : (lane - 1);
        const float prx = __shfl(px, pidx);
        const float pry = __shfl(py, pidx);

        // inside tests. Rp is the IDENTICAL expression lane pidx evaluates for
        // Rc, applied to the shuffled coords → bit-identical result, and it
        // removes a dependent __shfl(ins_c) from the serial chain.
        const float Rc = (c2x - c1x) * (py  - c1y) - (c2y - c1y) * (px  - c1x);
        const float Rp = (c2x - c1x) * (pry - c1y) - (c2y - c1y) * (prx - c1x);
        const bool ins_c = (Rc <= 0.0f);
        const bool ins_p = (Rp <= 0.0f);

        const bool valid  = (lane < n);
        const bool emit_i = valid && (ins_c != ins_p);
        const bool emit_c = valid && ins_c;

        const unsigned long long bi = __ballot(emit_i ? 1 : 0);
        const unsigned long long bc = __ballot(emit_c ? 1 : 0);

        // Fast path (wave-uniform): no crossings ⇒ cyclically all valid lanes
        // are on the same side ⇒ polygon unchanged (all inside: the LDS
        // round-trip would be the identity permutation, off==lane) or empty.
        if (bi == 0ULL) {
            if (bc == 0ULL) { n = 0; break; }   // all outside → empty
            continue;                            // all inside → unchanged
        }

        // cumsum offsets via ballots (matches jnp.cumsum(cnt) - cnt)
        const int off   = lower_popcount(bi) + lower_popcount(bc);
        const int total = __popcll(bi) + __popcll(bc);

        // intersection of line(prev,cur) with line(c1,c2) — reference arithmetic
        const float dx12 = px - prx, dy12 = py - pry;
        const float dx34 = c2x - c1x;
        const float m1 = dy12 / safe_(dx12);
        const float b1 = pry - m1 * prx;
        const float m2 = (c2y - c1y) / safe_(dx34);
        const float b2 = c1y - m2 * c1x;
        const float xg = (b2 - b1) / safe_(m1 - m2);
        const float yg = m1 * xg + b1;
        float ix, iy;
        if (dx12 == 0.0f)      { ix = prx; iy = m2 * prx + b2; }   // vert1 wins
        else if (dx34 == 0.0f) { ix = c1x; iy = m1 * c1x + b1; }   // vert2
        else                   { ix = xg;  iy = yg; }

        if (emit_i) {
            const int p0 = off;                           // writes >= MAXN dumped
            if (p0 < MAXN) { bufx[wave][p0] = ix; bufy[wave][p0] = iy; }
        }
        if (emit_c) {
            const int p1 = off + (emit_i ? 1 : 0);
            if (p1 < MAXN) { bufx[wave][p1] = px; bufy[wave][p1] = py; }
        }

        n = (total < MAXN) ? total : MAXN;
        px = (lane < n) ? bufx[wave][lane] : 0.0f;        // ref buf is zero-filled
        py = (lane < n) ? bufy[wave][lane] : 0.0f;
    }

    // ---- _area_padded (with the reference's duplicated 0->1 edge term) ----
    auto area = [&](float x, float y, int nn) -> float {
        const int ns = (nn > 0) ? nn : 1;
        const int nxt = (lane + 1 == ns) ? 0 : (lane + 1);
        const float xn = __shfl(x, nxt);
        const float yn = __shfl(y, nxt);
        const bool val = (lane < nn);
        float l = val ? x * yn : 0.0f;
        float r = val ? y * xn : 0.0f;
        #pragma unroll
        for (int o = 32; o > 0; o >>= 1) {
            l += __shfl_xor(l, o);
            r += __shfl_xor(r, o);
        }
        const int i1 = (ns > 1) ? 1 : 0;
        const float x0 = __shfl(x, 0),  y0 = __shfl(y, 0);
        const float xi = __shfl(x, i1), yi = __shfl(y, i1);
        if (nn > 0) { l += x0 * yi; r += y0 * xi; }
        return fabsf(0.5f * (r - l));
    };

    const float a_i = area(px, py, n);
    const float a_p = area(sx, sy, V);
    const float a_g = area(cx, cy, V);

    const float inter = ((a_i == 0.0f) ? fminf(a_p, a_g) : 0.0f) + a_i;
    const float uni   = a_g + a_p - inter;
    const float iou   = inter / (uni + 1e-6f);

    if (live && lane == 0) {
        // agent-scope release store → visible to the acquiring last block
        __hip_atomic_store(&iou_res[pu], iou * mval,
                           __ATOMIC_RELEASE, __HIP_MEMORY_SCOPE_AGENT);
    }

    // ---- last-block-done finalize (poison-base counter, no reset needed) ----
    // __syncthreads() drains vmcnt before s_barrier, so every wave's store
    // above is globally complete before thread 0 bumps the counter.
    __syncthreads();
    if (threadIdx.x == 0) {
        const unsigned int base = __hip_atomic_load(
            &ws_u32[16], __ATOMIC_RELAXED, __HIP_MEMORY_SCOPE_AGENT);
        const unsigned int old = __hip_atomic_fetch_add(
            &ws_u32[0], 1u, __ATOMIC_ACQ_REL, __HIP_MEMORY_SCOPE_AGENT);
        last_flag = ((unsigned int)(old - base) == (unsigned int)(nblocks - 1)) ? 1 : 0;
    }
    __syncthreads();
    if (last_flag == 0) return;

    __threadfence();   // acquire for the whole block (runs once per dispatch)

    // Bit-identical to the verified poly_finalize_kernel: same 256-thread
    // loads, same order, same shuffle tree.
    float si = 0.0f, sm = 0.0f;
    for (int i = threadIdx.x; i < BK; i += 256) {
        si += __hip_atomic_load(&iou_res[i], __ATOMIC_RELAXED, __HIP_MEMORY_SCOPE_AGENT);
        sm += mask[i];
    }
    #pragma unroll
    for (int o = 32; o > 0; o >>= 1) {
        si += __shfl_xor(si, o);
        sm += __shfl_xor(sm, o);
    }
    if (lane == 0) { red_a[wave] = si; red_c[wave] = sm; }
    __syncthreads();
    if (threadIdx.x == 0) {
        const float ti = red_a[0] + red_a[1] + red_a[2] + red_a[3];
        const float tm = red_c[0] + red_c[1] + red_c[2] + red_c[3];
        out[0] = 1.0f - ti / (tm + 1e-6f);
        // Restore the counter to its pre-run value so the next replay works
        // even if the harness skips re-poisoning (all other blocks' adds have
        // already completed — ours returned the final ticket).
        const unsigned int base = __hip_atomic_load(
            &ws_u32[16], __ATOMIC_RELAXED, __HIP_MEMORY_SCOPE_AGENT);
        __hip_atomic_store(&ws_u32[0], base,
                           __ATOMIC_RELAXED, __HIP_MEMORY_SCOPE_AGENT);
    }
}

extern "C" void kernel_launch(void* const* d_in, const int* in_sizes, int n_in,
                              void* d_out, int out_size, void* d_ws, size_t ws_size,
                              hipStream_t stream) {
    const float* output = (const float*)d_in[0];
    const float* mask   = (const float*)d_in[1];
    const int*   ind    = (const int*)d_in[2];
    const float* target = (const float*)d_in[3];

    const int BK = in_sizes[1];                 // B*K (mask elements)
    const int B  = 16;                          // per setup_inputs
    const int K  = BK / B;
    const int HW = in_sizes[0] / (B * 2 * V);   // 256*256

    const int grid = (BK + WAVES_PER_BLOCK - 1) / WAVES_PER_BLOCK;

    unsigned int* ws_u32 = (unsigned int*)d_ws;             // [0]=counter, [16]=base
    float* iou_res = (float*)((char*)d_ws + 256);           // [BK] floats

    poly_iou_fused_kernel<<<grid, 64 * WAVES_PER_BLOCK, 0, stream>>>(
        output, mask, ind, target, ws_u32, iou_res, (float*)d_out,
        BK, K, HW, grid);
}

// Round 4
// 173.763 us; speedup vs baseline: 1.1681x; 1.1681x over previous
//
#include <hip/hip_runtime.h>

#define V 16
#define MAXN 64
#define WAVES_PER_BLOCK 4

__device__ __forceinline__ float safe_(float d) { return (d == 0.0f) ? 1.0f : d; }

// popcount(m & ((1<<lane)-1)) in 2 instructions
__device__ __forceinline__ int lower_popcount(unsigned long long m) {
    return __builtin_amdgcn_mbcnt_hi((unsigned)(m >> 32),
           __builtin_amdgcn_mbcnt_lo((unsigned)m, 0));
}

// One wave (64 lanes) per polygon pair. lane = vertex slot (MAXN==64).
// Two-kernel structure. DO NOT fuse the finalize into this kernel: measured
// twice (R1 +23us with a memset node, R3 +28us with a poison-base counter and
// no memset) — the single-kernel cross-block-counter shape regresses in this
// harness. Two plain kernel dispatches is the verified fast graph shape
// (174.3 / 175.2 us on clean runs).
// NOTE: no explicit LDS fences — DS ops from a single wave are processed in
// program order by the LDS unit; compiler inserts lgkmcnt for register deps.
__global__ __launch_bounds__(256) void poly_iou_kernel(
    const float* __restrict__ output,  // [B, 2V, HW]
    const float* __restrict__ mask,    // [B, K]
    const int*   __restrict__ ind,     // [B, K]
    const float* __restrict__ target,  // [B, K, 2V]
    float* __restrict__ iou_ws,        // [BK]: iou * mask per pair
    int BK, int K, int HW)
{
    __shared__ float bufx[WAVES_PER_BLOCK][MAXN];
    __shared__ float bufy[WAVES_PER_BLOCK][MAXN];

    const int lane = threadIdx.x & 63;
    const int wave = threadIdx.x >> 6;
    int pair = blockIdx.x * WAVES_PER_BLOCK + wave;
    const bool live = pair < BK;
    if (!live) pair = 0;                 // keep wave running (uniform control)
    // pair is wave-uniform by construction → pin it to an SGPR so ind/mask
    // loads go down the scalar-memory path, off the vector critical path.
    const int pu = __builtin_amdgcn_readfirstlane(pair);
    const int b  = pu / K;

    const int   idx  = ind[pu];          // scalar load, issued early
    const float mval = mask[pu];         // scalar load, issued early

    // ---- load subject (pred, gathered) and clip (target) polygons ----
    float px = 0.0f, py = 0.0f;          // working poly[lane]
    float sx = 0.0f, sy = 0.0f;          // subject copy (for a_p)
    float cx = 0.0f, cy = 0.0f;          // clip vertex   (for edges + a_g)
    if (lane < V) {
        const float* ob = output + ((size_t)b * (2 * V)) * (size_t)HW;
        sx = ob[(size_t)(2 * lane) * HW + idx];
        sy = ob[(size_t)(2 * lane + 1) * HW + idx];
        const float2 t2 = ((const float2*)(target + (size_t)pu * (2 * V)))[lane];
        cx = t2.x;
        cy = t2.y;
        px = sx; py = sy;
    }
    int n = V;

    // ---- Sutherland–Hodgman clip: 16 edges (c1=clip[t-1], c2=clip[t]) ----
    for (int t = 0; t < V; ++t) {
        if (n == 0) break;               // wave-uniform

        const int t1 = (t + V - 1) & (V - 1);
        const float c1x = __shfl(cx, t1), c1y = __shfl(cy, t1);
        const float c2x = __shfl(cx, t),  c2y = __shfl(cy, t);

        // prev index: (lane-1) mod n; only lanes < n matter
        const int pidx = (lane == 0) ? (n - 1) : (lane - 1);
        const float prx = __shfl(px, pidx);
        const float pry = __shfl(py, pidx);

        // inside tests. Rp is the IDENTICAL expression lane pidx evaluates for
        // Rc, applied to the shuffled coords → bit-identical result, and it
        // removes a dependent __shfl(ins_c) from the serial chain.
        const float Rc = (c2x - c1x) * (py  - c1y) - (c2y - c1y) * (px  - c1x);
        const float Rp = (c2x - c1x) * (pry - c1y) - (c2y - c1y) * (prx - c1x);
        const bool ins_c = (Rc <= 0.0f);
        const bool ins_p = (Rp <= 0.0f);

        const bool valid  = (lane < n);
        const bool emit_i = valid && (ins_c != ins_p);
        const bool emit_c = valid && ins_c;

        const unsigned long long bi = __ballot(emit_i ? 1 : 0);
        const unsigned long long bc = __ballot(emit_c ? 1 : 0);

        // Fast path (wave-uniform): no crossings ⇒ cyclically all valid lanes
        // are on the same side ⇒ polygon unchanged (all inside: the LDS
        // round-trip would be the identity permutation, off==lane) or empty.
        if (bi == 0ULL) {
            if (bc == 0ULL) { n = 0; break; }   // all outside → empty
            continue;                            // all inside → unchanged
        }

        // cumsum offsets via ballots (matches jnp.cumsum(cnt) - cnt)
        const int off   = lower_popcount(bi) + lower_popcount(bc);
        const int total = __popcll(bi) + __popcll(bc);

        // intersection of line(prev,cur) with line(c1,c2) — reference arithmetic
        const float dx12 = px - prx, dy12 = py - pry;
        const float dx34 = c2x - c1x;
        const float m1 = dy12 / safe_(dx12);
        const float b1 = pry - m1 * prx;
        const float m2 = (c2y - c1y) / safe_(dx34);
        const float b2 = c1y - m2 * c1x;
        const float xg = (b2 - b1) / safe_(m1 - m2);
        const float yg = m1 * xg + b1;
        float ix, iy;
        if (dx12 == 0.0f)      { ix = prx; iy = m2 * prx + b2; }   // vert1 wins
        else if (dx34 == 0.0f) { ix = c1x; iy = m1 * c1x + b1; }   // vert2
        else                   { ix = xg;  iy = yg; }

        if (emit_i) {
            const int p0 = off;                           // writes >= MAXN dumped
            if (p0 < MAXN) { bufx[wave][p0] = ix; bufy[wave][p0] = iy; }
        }
        if (emit_c) {
            const int p1 = off + (emit_i ? 1 : 0);
            if (p1 < MAXN) { bufx[wave][p1] = px; bufy[wave][p1] = py; }
        }

        n = (total < MAXN) ? total : MAXN;
        px = (lane < n) ? bufx[wave][lane] : 0.0f;        // ref buf is zero-filled
        py = (lane < n) ? bufy[wave][lane] : 0.0f;
    }

    // ---- _area_padded (with the reference's duplicated 0->1 edge term) ----
    auto area = [&](float x, float y, int nn) -> float {
        const int ns = (nn > 0) ? nn : 1;
        const int nxt = (lane + 1 == ns) ? 0 : (lane + 1);
        const float xn = __shfl(x, nxt);
        const float yn = __shfl(y, nxt);
        const bool val = (lane < nn);
        float l = val ? x * yn : 0.0f;
        float r = val ? y * xn : 0.0f;
        #pragma unroll
        for (int o = 32; o > 0; o >>= 1) {
            l += __shfl_xor(l, o);
            r += __shfl_xor(r, o);
        }
        const int i1 = (ns > 1) ? 1 : 0;
        const float x0 = __shfl(x, 0),  y0 = __shfl(y, 0);
        const float xi = __shfl(x, i1), yi = __shfl(y, i1);
        if (nn > 0) { l += x0 * yi; r += y0 * xi; }
        return fabsf(0.5f * (r - l));
    };

    const float a_i = area(px, py, n);
    const float a_p = area(sx, sy, V);
    const float a_g = area(cx, cy, V);

    const float inter = ((a_i == 0.0f) ? fminf(a_p, a_g) : 0.0f) + a_i;
    const float uni   = a_g + a_p - inter;
    const float iou   = inter / (uni + 1e-6f);

    if (live && lane == 0) {
        iou_ws[pu] = iou * mval;                  // no atomics
    }
}

// Deterministic single-block reduction of iou*mask and mask sums.
// (Same 256-thread order as the verified baseline → bit-identical result.)
__global__ __launch_bounds__(256) void poly_finalize_kernel(
    const float* __restrict__ iou_ws,
    const float* __restrict__ mask,
    float* __restrict__ out, int BK)
{
    float si = 0.0f, sm = 0.0f;
    for (int i = threadIdx.x; i < BK; i += 256) {
        si += iou_ws[i];
        sm += mask[i];
    }
    #pragma unroll
    for (int o = 32; o > 0; o >>= 1) {
        si += __shfl_xor(si, o);
        sm += __shfl_xor(sm, o);
    }
    __shared__ float a[4], c[4];
    const int wave = threadIdx.x >> 6;
    if ((threadIdx.x & 63) == 0) { a[wave] = si; c[wave] = sm; }
    __syncthreads();
    if (threadIdx.x == 0) {
        const float ti = a[0] + a[1] + a[2] + a[3];
        const float tm = c[0] + c[1] + c[2] + c[3];
        out[0] = 1.0f - ti / (tm + 1e-6f);
    }
}

extern "C" void kernel_launch(void* const* d_in, const int* in_sizes, int n_in,
                              void* d_out, int out_size, void* d_ws, size_t ws_size,
                              hipStream_t stream) {
    const float* output = (const float*)d_in[0];
    const float* mask   = (const float*)d_in[1];
    const int*   ind    = (const int*)d_in[2];
    const float* target = (const float*)d_in[3];
    float* out = (float*)d_out;
    float* iou_ws = (float*)d_ws;

    const int BK = in_sizes[1];                 // B*K (mask elements)
    const int B  = 16;                          // per setup_inputs
    const int K  = BK / B;
    const int HW = in_sizes[0] / (B * 2 * V);   // 256*256

    const int grid = (BK + WAVES_PER_BLOCK - 1) / WAVES_PER_BLOCK;
    poly_iou_kernel<<<grid, 64 * WAVES_PER_BLOCK, 0, stream>>>(
        output, mask, ind, target, iou_ws, BK, K, HW);
    poly_finalize_kernel<<<1, 256, 0, stream>>>(iou_ws, mask, out, BK);
}